// Round 5
// baseline (211.160 us; speedup 1.0000x reference)
//
#include <hip/hip_runtime.h>
#include <hip/hip_bf16.h>

// Problem constants: B=2, T=2048, D=1024, H=16, DK=64
constexpr int Bc = 2;
constexpr int Tc = 2048;
constexpr int Mc = Bc * Tc;  // 4096

typedef __attribute__((ext_vector_type(8))) __bf16 bf16x8;
typedef __attribute__((ext_vector_type(4))) __bf16 bf16x4;
typedef __attribute__((ext_vector_type(4))) float floatx4;

__device__ __forceinline__ void gl_lds16(const void* g, void* l) {
    __builtin_amdgcn_global_load_lds(
        (const __attribute__((address_space(1))) void*)g,
        (__attribute__((address_space(3))) void*)l, 16, 0, 0);
}

// ---------------------------------------------------------------------------
// Prep: z<4 -> weight transpose+convert (Wq/Wk/Wv -> Wqkv sections, Wo -> Wot);
// z>=4 -> x fp32->bf16 convert slice (z-4), 1024 blocks total for BW.
// ---------------------------------------------------------------------------
__global__ __launch_bounds__(256) void prep_all(const float* __restrict__ x,
                                                const float* __restrict__ Wq,
                                                const float* __restrict__ Wk,
                                                const float* __restrict__ Wv,
                                                const float* __restrict__ Wo,
                                                __bf16* __restrict__ xb,
                                                __bf16* __restrict__ Wqkv,
                                                __bf16* __restrict__ Wot) {
    const int z = blockIdx.z;
    const int tid = threadIdx.x;
    if (z >= 4) {
        // convert: slice (z-4), block lb -> 4096 contiguous floats
        const int lb = blockIdx.y * 16 + blockIdx.x;
        const size_t base = ((size_t)(z - 4) * 256 + lb) * 4096;
#pragma unroll
        for (int it = 0; it < 4; ++it) {
            const size_t i = base + (size_t)(it * 256 + tid) * 4;
            const float4 v = *(const float4*)(x + i);
            bf16x4 r;
            r[0] = (__bf16)v.x; r[1] = (__bf16)v.y;
            r[2] = (__bf16)v.z; r[3] = (__bf16)v.w;
            *(bf16x4*)(xb + i) = r;
        }
        return;
    }
    __shared__ float t[64][65];
    const float* W = (z == 0) ? Wq : (z == 1) ? Wk : (z == 2) ? Wv : Wo;
    __bf16* Wt = (z < 3) ? Wqkv + (size_t)z * 1024 * 1024 : Wot;
    const int k0 = blockIdx.y * 64, n0 = blockIdx.x * 64;
    const int c = tid & 63, r0 = tid >> 6;
#pragma unroll
    for (int i = 0; i < 16; ++i)
        t[r0 + i * 4][c] = W[(size_t)(k0 + r0 + i * 4) * 1024 + n0 + c];
    __syncthreads();
#pragma unroll
    for (int i = 0; i < 16; ++i) {
        const int r = r0 + i * 4;
        Wt[(size_t)(n0 + r) * 1024 + k0 + c] = (__bf16)t[c][r];
    }
}

// ---------------------------------------------------------------------------
// bf16 MFMA GEMM: C[M,TNgrid] = A[M,K] @ Bt[N,K]^T + bias.
// 128xTN tile (TN=128 or 64), 256 threads = 4 waves.
// FUSE_VT: columns >=2048 (the V projection) stream transposed into
// Vt[bh][d][t] instead of C.
// ---------------------------------------------------------------------------
template <int TN, bool BF16_OUT, bool FUSE_VT>
__global__ __launch_bounds__(256) void gemm_bt(const __bf16* __restrict__ A,
                                               const __bf16* __restrict__ Bt,
                                               const float* __restrict__ b0,
                                               const float* __restrict__ b1,
                                               const float* __restrict__ b2,
                                               void* __restrict__ Cv,
                                               __bf16* __restrict__ Vt,
                                               int K, int ldc) {
    constexpr int NI = TN / 32;
    __shared__ __bf16 As[128 * 32];
    __shared__ __bf16 Bs[TN * 32];
    const int tid = threadIdx.x, lane = tid & 63, wave = tid >> 6;
    const int wm = wave & 1, wn = wave >> 1;
    const int bm = blockIdx.y * 128, bn = blockIdx.x * TN;
    const __bf16* Ab = A + (size_t)bm * K;
    const __bf16* Bb = Bt + (size_t)bn * K;
    const int quad = lane >> 4, tm = lane & 15;

    floatx4 acc[4][NI] = {};

    for (int k0 = 0; k0 < K; k0 += 32) {
#pragma unroll
        for (int i = 0; i < 2; ++i) {
            const int s = i * 256 + tid;
            gl_lds16(Ab + (size_t)(s >> 2) * K + k0 + (s & 3) * 8, As + s * 8);
        }
        if (TN == 128) {
#pragma unroll
            for (int i = 0; i < 2; ++i) {
                const int s = i * 256 + tid;
                gl_lds16(Bb + (size_t)(s >> 2) * K + k0 + (s & 3) * 8, Bs + s * 8);
            }
        } else {
            const int s = tid;
            gl_lds16(Bb + (size_t)(s >> 2) * K + k0 + (s & 3) * 8, Bs + s * 8);
        }
        __syncthreads();
        bf16x8 af[4], bfv[NI];
#pragma unroll
        for (int mi = 0; mi < 4; ++mi)
            af[mi] = *(const bf16x8*)(As + (wm * 64 + mi * 16 + tm) * 32 + quad * 8);
#pragma unroll
        for (int ni = 0; ni < NI; ++ni)
            bfv[ni] = *(const bf16x8*)(Bs + (wn * (TN / 2) + ni * 16 + tm) * 32 + quad * 8);
#pragma unroll
        for (int mi = 0; mi < 4; ++mi)
#pragma unroll
            for (int ni = 0; ni < NI; ++ni)
                acc[mi][ni] = __builtin_amdgcn_mfma_f32_16x16x32_bf16(
                    af[mi], bfv[ni], acc[mi][ni], 0, 0, 0);
        __syncthreads();
    }

#pragma unroll
    for (int ni = 0; ni < NI; ++ni) {
        const int gc = bn + wn * (TN / 2) + ni * 16 + tm;
        const float bias = (gc < 1024) ? b0[gc]
                         : (gc < 2048) ? b1[gc - 1024]
                                       : b2[gc - 2048];
#pragma unroll
        for (int mi = 0; mi < 4; ++mi) {
            const int gr0 = bm + wm * 64 + mi * 16 + quad * 4;
            if (FUSE_VT && gc >= 2048) {
                bf16x4 pv;
#pragma unroll
                for (int r = 0; r < 4; ++r) pv[r] = (__bf16)(acc[mi][ni][r] + bias);
                const int bb = gr0 >> 11, tloc = gr0 & 2047;
                const int hh = (gc - 2048) >> 6, dd = gc & 63;
                *(bf16x4*)(Vt + ((size_t)(bb * 16 + hh) * 64 + dd) * 2048 + tloc) = pv;
            } else if (BF16_OUT) {
#pragma unroll
                for (int r = 0; r < 4; ++r)
                    ((__bf16*)Cv)[(size_t)(gr0 + r) * ldc + gc] =
                        (__bf16)(acc[mi][ni][r] + bias);
            } else {
#pragma unroll
                for (int r = 0; r < 4; ++r)
                    ((float*)Cv)[(size_t)(gr0 + r) * ldc + gc] =
                        acc[mi][ni][r] + bias;
            }
        }
    }
}

// ---------------------------------------------------------------------------
// MFMA flash attention (causal), S^T formulation, unpaired 1024 blocks.
// Grid (32, B*H), 256 threads = 4 waves; q-tile = (bx+by)&31 (diagonal
// swizzle: co-resident same-bx blocks get q-tiles spread by 8 -> balanced
// per-CU work). Wave w owns q rows w*16..w*16+15.
// S^T = K.Q^T: lane c = q-row, regs = k -> in-lane softmax + 2 shuffles;
// P feeds PV from registers (slot-permuted O^T = V^T.P^T).
// K/V tiles (64) double-buffered via swizzled global_load_lds; all frag
// LDS offsets hoisted (sw = c&7 is loop-invariant); staging via 4 running
// pointers.
// ---------------------------------------------------------------------------
__global__ __launch_bounds__(256) void attn_mfma(const __bf16* __restrict__ QK,
                                                 const __bf16* __restrict__ Vt,
                                                 __bf16* __restrict__ ctx) {
    constexpr float Cf = 0.18033688011112042f;  // (1/sqrt(64)) * log2(e)
    constexpr float NEG = -1e30f;

    __shared__ __bf16 Ks[2][64 * 64];
    __shared__ __bf16 Vts[2][64 * 64];

    const int tid = threadIdx.x, lane = tid & 63, w = tid >> 6;
    const int c = lane & 15, quad = lane >> 4;
    const int bh = blockIdx.y, b = bh >> 4, h = bh & 15;
    const int qt = ((int)blockIdx.x + (int)blockIdx.y) & 31;
    const int nk = qt + 1;

    const __bf16* Qb = QK + (size_t)(b * Tc) * 2048 + h * 64;
    const __bf16* Kb = Qb + 1024;
    const __bf16* Vtb = Vt + (size_t)bh * 64 * 2048;

    // Q fragments (B-operand: n = q-row = lane&15), held for the whole block
    const __bf16* qr = Qb + (size_t)(qt * 64 + w * 16 + c) * 2048;
    const bf16x8 qf0 = *(const bf16x8*)(qr + quad * 8);
    const bf16x8 qf1 = *(const bf16x8*)(qr + 32 + quad * 8);

    float m = NEG, l = 0.f;
    floatx4 oa[4] = {};

    // --- hoisted frag LDS offsets (element units; sw = c&7 loop-invariant) ---
    const int sw = c & 7;
    int koff0[4], koff1[4];
#pragma unroll
    for (int ni = 0; ni < 4; ++ni) {
        const int krow = ni * 16 + c;
        koff0[ni] = krow * 64 + (quad ^ sw) * 8;
        koff1[ni] = krow * 64 + ((4 + quad) ^ sw) * 8;
    }
    int voff0[4][2], voff1[4][2];
#pragma unroll
    for (int di = 0; di < 4; ++di) {
        const int vrow = di * 16 + c;
#pragma unroll
        for (int pr = 0; pr < 2; ++pr) {
            const int lc0 = (4 * pr + (quad >> 1)) ^ sw;
            const int lc1 = (4 * pr + 2 + (quad >> 1)) ^ sw;
            voff0[di][pr] = vrow * 64 + lc0 * 8 + (quad & 1) * 4;
            voff1[di][pr] = vrow * 64 + lc1 * 8 + (quad & 1) * 4;
        }
    }

    // --- staging pointers (swizzled: phys chunk s holds logical col
    //     (s&7)^(row&7)); s0 = tid, s1 = tid+256 -> rows r, r+32 ---
    const int srow = tid >> 3;
    const int slc = (tid & 7) ^ (srow & 7);
    const __bf16* kg0 = Kb + (size_t)srow * 2048 + slc * 8;
    const __bf16* kg1 = kg0 + (size_t)32 * 2048;
    const __bf16* vg0 = Vtb + (size_t)srow * 2048 + slc * 8;
    const __bf16* vg1 = vg0 + (size_t)32 * 2048;
    __bf16* kd0 = &Ks[0][tid * 8];
    __bf16* vd0 = &Vts[0][tid * 8];

    // stage tile 0 into buf 0
    gl_lds16(kg0, kd0);
    gl_lds16(kg1, kd0 + 256 * 8);
    gl_lds16(vg0, vd0);
    gl_lds16(vg1, vd0 + 256 * 8);
    kg0 += 64 * 2048; kg1 += 64 * 2048;
    vg0 += 64; vg1 += 64;
    __syncthreads();

    for (int kt = 0; kt < nk; ++kt) {
        const int buf = kt & 1;
        if (kt + 1 < nk) {
            __bf16* kd = &Ks[buf ^ 1][tid * 8];
            __bf16* vd = &Vts[buf ^ 1][tid * 8];
            gl_lds16(kg0, kd);
            gl_lds16(kg1, kd + 256 * 8);
            gl_lds16(vg0, vd);
            gl_lds16(vg1, vd + 256 * 8);
            kg0 += 64 * 2048; kg1 += 64 * 2048;
            vg0 += 64; vg1 += 64;
        }
        const __bf16* ks = Ks[buf];
        const __bf16* vs = Vts[buf];

        // --- S^T = K.Q^T : sv[ni][r] = S[k=16ni+quad*4+r][q=c] ---
        float sv[4][4];
#pragma unroll
        for (int ni = 0; ni < 4; ++ni) {
            const bf16x8 kb0 = *(const bf16x8*)(ks + koff0[ni]);
            const bf16x8 kb1 = *(const bf16x8*)(ks + koff1[ni]);
            floatx4 a = {};
            a = __builtin_amdgcn_mfma_f32_16x16x32_bf16(kb0, qf0, a, 0, 0, 0);
            a = __builtin_amdgcn_mfma_f32_16x16x32_bf16(kb1, qf1, a, 0, 0, 0);
#pragma unroll
            for (int r = 0; r < 4; ++r) sv[ni][r] = a[r];
        }

        // --- online softmax (k in regs; reduce in-lane + 2 shuffles) ---
        if (kt == qt) {  // diagonal: mask k_loc > q_loc
#pragma unroll
            for (int ni = 0; ni < 4; ++ni)
#pragma unroll
                for (int r = 0; r < 4; ++r)
                    if (ni * 16 + quad * 4 + r > w * 16 + c) sv[ni][r] = NEG;
        }
        float rm = sv[0][0];
#pragma unroll
        for (int ni = 0; ni < 4; ++ni)
#pragma unroll
            for (int r = 0; r < 4; ++r) rm = fmaxf(rm, sv[ni][r]);
        rm = fmaxf(rm, __shfl_xor(rm, 16));
        rm = fmaxf(rm, __shfl_xor(rm, 32));
        const float nm = fmaxf(m, rm);
        const float alpha = __builtin_exp2f((m - nm) * Cf);
        const float nmc = -nm * Cf;
        float sum = 0.f;
#pragma unroll
        for (int ni = 0; ni < 4; ++ni)
#pragma unroll
            for (int r = 0; r < 4; ++r) {
                const float p = __builtin_exp2f(fmaf(sv[ni][r], Cf, nmc));
                sv[ni][r] = p;
                sum += p;
            }
        sum += __shfl_xor(sum, 16);
        sum += __shfl_xor(sum, 32);
        m = nm;
        l = l * alpha + sum;

        // pack P into B-frags (slot quad*8+j <-> t = 16*(2pr+(j>=4)) + quad*4+(j&3))
        bf16x8 pb[2];
#pragma unroll
        for (int pr = 0; pr < 2; ++pr)
#pragma unroll
            for (int j = 0; j < 4; ++j) {
                pb[pr][j] = (__bf16)sv[pr * 2][j];
                pb[pr][4 + j] = (__bf16)sv[pr * 2 + 1][j];
            }

        // --- rescale O, O^T += V^T.P^T ---
#pragma unroll
        for (int di = 0; di < 4; ++di)
#pragma unroll
            for (int r = 0; r < 4; ++r) oa[di][r] *= alpha;
#pragma unroll
        for (int di = 0; di < 4; ++di) {
#pragma unroll
            for (int pr = 0; pr < 2; ++pr) {
                const bf16x4 va = *(const bf16x4*)(vs + voff0[di][pr]);
                const bf16x4 vb = *(const bf16x4*)(vs + voff1[di][pr]);
                bf16x8 vf;
#pragma unroll
                for (int j = 0; j < 4; ++j) { vf[j] = va[j]; vf[4 + j] = vb[j]; }
                oa[di] = __builtin_amdgcn_mfma_f32_16x16x32_bf16(
                    vf, pb[pr], oa[di], 0, 0, 0);
            }
        }
        __syncthreads();
    }

    // --- epilogue: lane holds O^T[d=di*16+quad*4+r][q=c] ---
    const float inv = 1.f / l;
    __bf16* cp = ctx + (size_t)(b * Tc + qt * 64 + w * 16 + c) * 1024 +
                 h * 64 + quad * 4;
#pragma unroll
    for (int di = 0; di < 4; ++di) {
        bf16x4 rv;
#pragma unroll
        for (int r = 0; r < 4; ++r) rv[r] = (__bf16)(oa[di][r] * inv);
        *(bf16x4*)(cp + di * 16) = rv;
    }
}

// ---------------------------------------------------------------------------
// kernel_launch. Workspace (bf16 el): xb 4M | Wqkv 3M | Wot 1M | QKb 8M |
// Vt 4M | ctxb 4M = 24M el = 48 MB.
// ---------------------------------------------------------------------------
extern "C" void kernel_launch(void* const* d_in, const int* in_sizes, int n_in,
                              void* d_out, int out_size, void* d_ws, size_t ws_size,
                              hipStream_t stream) {
    const float* x  = (const float*)d_in[0];
    const float* Wq = (const float*)d_in[1];
    const float* bq = (const float*)d_in[2];
    const float* Wk = (const float*)d_in[3];
    const float* bk = (const float*)d_in[4];
    const float* Wv = (const float*)d_in[5];
    const float* bv = (const float*)d_in[6];
    const float* Wo = (const float*)d_in[7];
    const float* bo = (const float*)d_in[8];

    __bf16* xb   = (__bf16*)d_ws;                    // [4096][1024]
    __bf16* Wqkv = xb + (size_t)Mc * 1024;           // [3072][1024] (B^T)
    __bf16* Wot  = Wqkv + (size_t)3072 * 1024;       // [1024][1024] (B^T)
    __bf16* QKb  = Wot + (size_t)1024 * 1024;        // [4096][2048]  Q|K
    __bf16* Vtw  = QKb + (size_t)Mc * 2048;          // [32][64][2048]
    __bf16* ctxb = Vtw + (size_t)32 * 64 * 2048;     // [4096][1024]

    prep_all<<<dim3(16, 16, 8), 256, 0, stream>>>(x, Wq, Wk, Wv, Wo,
                                                  xb, Wqkv, Wot);

    // QKV projection: N=3072; V columns stream transposed into Vtw
    gemm_bt<128, true, true><<<dim3(24, 32), 256, 0, stream>>>(
        xb, Wqkv, bq, bk, bv, QKb, Vtw, 1024, 2048);

    attn_mfma<<<dim3(32, 32), 256, 0, stream>>>(QKb, Vtw, ctxb);

    // Output projection: N=1024, fp32 out, 128x64 tiles for occupancy
    gemm_bt<64, false, false><<<dim3(16, 32), 256, 0, stream>>>(
        ctxb, Wot, bo, bo, bo, d_out, nullptr, 1024, 1024);
}